// Round 1
// 132.085 us; speedup vs baseline: 1.0752x; 1.0752x over previous
//
#include <hip/hip_runtime.h>
#include <hip/hip_bf16.h>

// Problem constants (fixed by the reference)
#define BATCH 8
#define NPTS  4096      // N
#define CCH   128      // C
#define KNN_K 16       // K

typedef __attribute__((ext_vector_type(8))) short  bf16x8;  // 8 bf16 = 4 VGPRs
typedef __attribute__((ext_vector_type(4))) float  f32x4;   // MFMA acc

// ---------------------------------------------------------------------------
// ws layout (bytes):
//   [0)          xTb   : B*N*C bf16      = 8,388,608
//   [8388608)    Wb    : C*C  bf16       =    32,768
//   [8421376)    scale : C fp32          =       512
//   [8421888)    bias  : C fp32          =       512
//   [8422400)    pts   : B*N float4(x,y,z,s) = 524,288
//   [8946688)    knn   : B*N*K u16       = 1,048,576
//   [9995264)    Zb    : B*N*C bf16      = 8,388,608   (Z = W@x, [B,N,C])
// total 18,383,872
// ---------------------------------------------------------------------------

static __device__ __forceinline__ short f2bf(float v) {
    __hip_bfloat16 h = __float2bfloat16(v);   // RNE
    return __builtin_bit_cast(short, h);
}

// LDS-tiled transpose: x [B,C,N] fp32 -> xTb [B,N,C] bf16.
__global__ __launch_bounds__(256) void transpose_kernel(
    const float* __restrict__ x, short* __restrict__ xTb)
{
    __shared__ short tile[64 * 66];
    const int tid = threadIdx.x;
    const int b   = blockIdx.x >> 7;         // 8 batches
    const int rem = blockIdx.x & 127;
    const int nt  = rem >> 1;                // 64 n-tiles of 64
    const int ct  = rem & 1;                 // 2 c-tiles of 64

    #pragma unroll
    for (int it = 0; it < 16; ++it) {
        const int idx = it * 256 + tid;
        const int cc  = idx >> 6;
        const int nn  = idx & 63;
        const float v = x[(size_t)(b * CCH + ct * 64 + cc) * NPTS + nt * 64 + nn];
        tile[cc * 66 + nn] = f2bf(v);
    }
    __syncthreads();
    #pragma unroll
    for (int it = 0; it < 16; ++it) {
        const int idx = it * 256 + tid;
        const int nn  = idx >> 6;
        const int cc  = idx & 63;
        xTb[(size_t)(b * NPTS + nt * 64 + nn) * CCH + ct * 64 + cc] = tile[cc * 66 + nn];
    }
}

// Small prep: W -> bf16; fold BN affine; xyz -> SoA float4 with |p|^2
__global__ __launch_bounds__(256) void small_prep_kernel(
    const float* __restrict__ xyz, const float* __restrict__ W,
    const float* __restrict__ gamma, const float* __restrict__ beta,
    const float* __restrict__ rmean, const float* __restrict__ rvar,
    short* __restrict__ Wb, float* __restrict__ scale, float* __restrict__ bias,
    float4* __restrict__ pts)
{
    const int t = blockIdx.x * 256 + threadIdx.x;   // grid covers B*N = 32768
    if (t < CCH * CCH) Wb[t] = f2bf(W[t]);
    if (t < CCH) {
        const float s = gamma[t] / sqrtf(rvar[t] + 1e-5f);
        scale[t] = s;
        bias[t]  = beta[t] - rmean[t] * s;
    }
    {
        #pragma clang fp contract(off)
        const float px = xyz[3 * t + 0];
        const float py = xyz[3 * t + 1];
        const float pz = xyz[3 * t + 2];
        const float s  = px * px + py * py + pz * pz;   // matches ref s = sum(xyz*xyz)
        pts[t] = make_float4(px, py, pz, s);
    }
}

// KNN, 4 queries per wave. lane = g*16+s. Top-16 list of each query lives
// across its group's 16 lanes (lane s = s-th smallest).
//
// v2: 4 candidates per lane per iteration (64 candidates per query per iter,
// 64 iterations). Amortizes loop control, prefetch pointer math, and the
// width-16 tau broadcast 4x vs the 1-candidate/lane version. The ballot +
// sorted-insert machinery runs at the same 16-candidate granularity and in
// the same ascending-j order (sub-chunks c=0..3 ascending, ffs ascending,
// strict <), so selection and tie-breaks are bit-identical to the reference.
// tau is refreshed once per 64 candidates; stale-tau survivors self-reject
// in the insert (dv >= bd[15] shifts nothing).
__global__ __launch_bounds__(256) void knn_kernel(
    const float4* __restrict__ pts, unsigned short* __restrict__ knn)
{
    const int lane = threadIdx.x & 63;
    const int wid  = threadIdx.x >> 6;
    const int g    = lane >> 4;                 // group (query) 0..3
    const int s    = lane & 15;                 // slot within group
    const int wq   = blockIdx.x * 16 + wid * 4; // first query of this wave
    const int b    = wq >> 12;                  // 4 queries never cross a batch
    const int i    = (wq & 4095) + g;           // this lane's query
    const float4* pb = pts + (b << 12);

    const float4 q = pb[i];                     // group-uniform

    float bd = 3.4e38f;                         // slot s: s-th smallest
    int   bj = 0;
    float tau = 3.4e38f;                        // group-uniform (lane copy)
    const bool sgt0 = (s > 0);
    const int  gsh  = g << 4;

    // Process one block of 64 candidates: lane covers j = jbase + 16*c + s,
    // c = 0..3 (immediate-offset loads from one base pointer).
    auto process = [&](const float4& p0, const float4& p1,
                       const float4& p2, const float4& p3, const int jbase) {
        float dd[4];
        {
            #pragma clang fp contract(off)
            dd[0] = (q.w + p0.w) - 2.0f * (q.x * p0.x + q.y * p0.y + q.z * p0.z);
            dd[1] = (q.w + p1.w) - 2.0f * (q.x * p1.x + q.y * p1.y + q.z * p1.z);
            dd[2] = (q.w + p2.w) - 2.0f * (q.x * p2.x + q.y * p2.y + q.z * p2.z);
            dd[3] = (q.w + p3.w) - 2.0f * (q.x * p3.x + q.y * p3.y + q.z * p3.z);
        }
        #pragma unroll
        for (int c = 0; c < 4; ++c) {
            const unsigned long long mask = __ballot(dd[c] < tau);
            unsigned sub = (unsigned)((mask >> gsh) & 0xFFFFull);
            while (__any(sub != 0)) {
                const bool has = (sub != 0);
                const int  l   = has ? (__ffs(sub) - 1) : 0;
                const float dvr = __shfl(dd[c], l, 16);      // group-local fetch
                const float dv  = has ? dvr : 3.4e38f;
                const int   jv  = jbase + c * 16 + l;
                sub = has ? (sub & (sub - 1)) : 0u;
                // sorted insert across the group's 16 lanes (ascending)
                const float pd = __shfl_up(bd, 1, 16);
                const int   pj = __shfl_up(bj, 1, 16);
                const bool lt  = dv < bd;
                const bool ltp = sgt0 && (dv < pd);
                bd = lt ? (ltp ? pd : dv) : bd;
                bj = lt ? (ltp ? pj : jv) : bj;
            }
        }
        tau = __shfl(bd, 15, 16);               // once per 64 candidates
    };

    const float4* lp = pb + s;                  // block 0 base for this lane
    float4 a0 = lp[0], a1 = lp[16], a2 = lp[32], a3 = lp[48];
    lp += 64;

    #pragma unroll 2
    for (int it = 0; it < 64; ++it) {
        // prefetch next block (clamped to pb on the last iter; values unused)
        const float4* np = (it < 63) ? lp : pb;
        const float4 n0 = np[0], n1 = np[16], n2 = np[32], n3 = np[48];
        process(a0, a1, a2, a3, it * 64);
        a0 = n0; a1 = n1; a2 = n2; a3 = n3;
        lp += 64;
    }

    unsigned short* o = knn + ((((size_t)b << 12) + i) << 4);
    o[s] = (unsigned short)bj;                  // 4 queries x 16 slots
}

// Dense GEMM: Z[g, c] = sum_k xTb[g, k] * W[c, k], Z bf16 [B*N, C].
// Wave = 16 rows x 128 cols; verified fragment mappings (A: m=lane&15,
// k=(lane>>4)*8+j; B: n=lane&15, same k-slice; C/D: col=lane&15,
// row=(lane>>4)*4+reg). W staged in LDS, pitch 136.
__global__ __launch_bounds__(256) void zgemm_kernel(
    const short* __restrict__ xTb, const short* __restrict__ Wb,
    short* __restrict__ Zb)
{
    __shared__ short sW[CCH * 136];
    const int lane = threadIdx.x & 63;
    const int wid  = threadIdx.x >> 6;
    const int kl   = lane & 15;
    const int q8   = (lane >> 4) * 8;

    #pragma unroll
    for (int it = 0; it < 8; ++it) {             // stage W: 16384 elems
        const int e = (it * 256 + threadIdx.x) * 8;
        const int r = e >> 7, c = e & 127;
        *(bf16x8*)(sW + r * 136 + c) = *(const bf16x8*)(Wb + e);
    }

    const int    G    = blockIdx.x * 64 + wid * 16 + kl;   // A-row (flat B*N)
    const size_t arow = (size_t)G * CCH;
    __syncthreads();

    const f32x4 zero = {0.f, 0.f, 0.f, 0.f};
    f32x4 acc[8];
    #pragma unroll
    for (int t = 0; t < 8; ++t) acc[t] = zero;

    #pragma unroll
    for (int kk = 0; kk < 4; ++kk) {
        const bf16x8 a = *(const bf16x8*)(xTb + arow + kk * 32 + q8);
        #pragma unroll
        for (int t = 0; t < 8; ++t) {
            const bf16x8 bf = *(const bf16x8*)(sW + (t * 16 + kl) * 136 + kk * 32 + q8);
            acc[t] = __builtin_amdgcn_mfma_f32_16x16x32_bf16(a, bf, acc[t], 0, 0, 0);
        }
    }

    const int rbase = blockIdx.x * 64 + wid * 16 + (lane >> 4) * 4;
    #pragma unroll
    for (int t = 0; t < 8; ++t)
        #pragma unroll
        for (int r = 0; r < 4; ++r)
            Zb[(size_t)(rbase + r) * CCH + t * 16 + kl] = f2bf(acc[t][r]);
}

// Gather + BN + ReLU + max-over-16, then coalesced store via LDS transpose.
// Block = 16 points; wave w handles 4 points serially; lane l covers channels
// 2l, 2l+1 (one dword per Z-row read; full 256B row per wave, coalesced).
__global__ __launch_bounds__(256) void gmax_kernel(
    const short* __restrict__ Zb, const unsigned short* __restrict__ knn,
    const float* __restrict__ scale, const float* __restrict__ bias,
    float* __restrict__ out)
{
    __shared__ float sm[16][132];
    const int lane = threadIdx.x & 63;
    const int wid  = threadIdx.x >> 6;
    const int n0   = blockIdx.x * 16;           // flat point base (B*N)
    const int b    = blockIdx.x >> 8;           // 256 blocks per batch
    const float s0 = scale[2 * lane],   s1 = scale[2 * lane + 1];
    const float t0 = bias[2 * lane],    t1 = bias[2 * lane + 1];

    for (int p = 0; p < 4; ++p) {
        const int n = n0 + wid * 4 + p;         // flat
        const unsigned short* kr = knn + (size_t)n * 16;
        float m0 = 0.f, m1 = 0.f;               // relu floor
        #pragma unroll
        for (int k = 0; k < 16; ++k) {
            const int r = (int)kr[k];           // within-batch row
            const unsigned v = *(const unsigned*)(Zb + ((size_t)(b * NPTS + r)) * CCH + 2 * lane);
            const float z0 = __uint_as_float(v << 16);
            const float z1 = __uint_as_float(v & 0xFFFF0000u);
            m0 = fmaxf(m0, s0 * z0 + t0);
            m1 = fmaxf(m1, s1 * z1 + t1);
        }
        sm[wid * 4 + p][2 * lane]     = m0;
        sm[wid * 4 + p][2 * lane + 1] = m1;
    }
    __syncthreads();

    const int c    = threadIdx.x & 127;
    const int half = threadIdx.x >> 7;
    float v[8];
    #pragma unroll
    for (int i = 0; i < 8; ++i) v[i] = sm[half * 8 + i][c];
    float4 f0 = {v[0], v[1], v[2], v[3]};
    float4 f1 = {v[4], v[5], v[6], v[7]};
    float* op = out + ((size_t)(b * CCH + c)) * NPTS + (n0 & 4095) + half * 8;
    *(float4*)op       = f0;
    *(float4*)(op + 4) = f1;
}

extern "C" void kernel_launch(void* const* d_in, const int* in_sizes, int n_in,
                              void* d_out, int out_size, void* d_ws, size_t ws_size,
                              hipStream_t stream)
{
    const float* xyz   = (const float*)d_in[0];
    const float* x     = (const float*)d_in[1];
    const float* W     = (const float*)d_in[2];
    const float* gamma = (const float*)d_in[3];
    const float* beta  = (const float*)d_in[4];
    const float* rmean = (const float*)d_in[5];
    const float* rvar  = (const float*)d_in[6];
    float* out = (float*)d_out;

    char* ws = (char*)d_ws;
    short*          xTb   = (short*)(ws);
    short*          Wb    = (short*)(ws + 8388608);
    float*          scale = (float*)(ws + 8421376);
    float*          bias  = (float*)(ws + 8421888);
    float4*         pts   = (float4*)(ws + 8422400);
    unsigned short* knn   = (unsigned short*)(ws + 8946688);
    short*          Zb    = (short*)(ws + 9995264);

    transpose_kernel<<<BATCH * 64 * 2, 256, 0, stream>>>(x, xTb);
    small_prep_kernel<<<BATCH * NPTS / 256, 256, 0, stream>>>(
        xyz, W, gamma, beta, rmean, rvar, Wb, scale, bias, pts);
    knn_kernel<<<BATCH * NPTS / 16, 256, 0, stream>>>(pts, knn);
    zgemm_kernel<<<BATCH * NPTS / 64, 256, 0, stream>>>(xTb, Wb, Zb);
    gmax_kernel<<<BATCH * NPTS / 16, 256, 0, stream>>>(Zb, knn, scale, bias, out);
}

// Round 2
// 116.733 us; speedup vs baseline: 1.2166x; 1.1315x over previous
//
#include <hip/hip_runtime.h>
#include <hip/hip_bf16.h>

// Problem constants (fixed by the reference)
#define BATCH 8
#define NPTS  4096      // N
#define CCH   128      // C
#define KNN_K 16       // K

typedef __attribute__((ext_vector_type(8))) short  bf16x8;  // 8 bf16 = 4 VGPRs
typedef __attribute__((ext_vector_type(4))) float  f32x4;   // MFMA acc

// ---------------------------------------------------------------------------
// ws layout (bytes):
//   [0)          xTb   : B*N*C bf16      = 8,388,608
//   [8388608)    Wb    : C*C  bf16       =    32,768
//   [8421376)    scale : C fp32          =       512
//   [8421888)    bias  : C fp32          =       512
//   [8422400)    pts   : B*N float4(x,y,z,s) = 524,288
//   [8946688)    knn   : B*N*K u16       = 1,048,576
//   [9995264)    Zb    : B*N*C bf16      = 8,388,608   (Z = W@x, [B,N,C])
// total 18,383,872
// ---------------------------------------------------------------------------

static __device__ __forceinline__ short f2bf(float v) {
    __hip_bfloat16 h = __float2bfloat16(v);   // RNE
    return __builtin_bit_cast(short, h);
}

// LDS-tiled transpose: x [B,C,N] fp32 -> xTb [B,N,C] bf16.
__global__ __launch_bounds__(256) void transpose_kernel(
    const float* __restrict__ x, short* __restrict__ xTb)
{
    __shared__ short tile[64 * 66];
    const int tid = threadIdx.x;
    const int b   = blockIdx.x >> 7;         // 8 batches
    const int rem = blockIdx.x & 127;
    const int nt  = rem >> 1;                // 64 n-tiles of 64
    const int ct  = rem & 1;                 // 2 c-tiles of 64

    #pragma unroll
    for (int it = 0; it < 16; ++it) {
        const int idx = it * 256 + tid;
        const int cc  = idx >> 6;
        const int nn  = idx & 63;
        const float v = x[(size_t)(b * CCH + ct * 64 + cc) * NPTS + nt * 64 + nn];
        tile[cc * 66 + nn] = f2bf(v);
    }
    __syncthreads();
    #pragma unroll
    for (int it = 0; it < 16; ++it) {
        const int idx = it * 256 + tid;
        const int nn  = idx >> 6;
        const int cc  = idx & 63;
        xTb[(size_t)(b * NPTS + nt * 64 + nn) * CCH + ct * 64 + cc] = tile[cc * 66 + nn];
    }
}

// Small prep: W -> bf16; fold BN affine; xyz -> SoA float4 with |p|^2
__global__ __launch_bounds__(256) void small_prep_kernel(
    const float* __restrict__ xyz, const float* __restrict__ W,
    const float* __restrict__ gamma, const float* __restrict__ beta,
    const float* __restrict__ rmean, const float* __restrict__ rvar,
    short* __restrict__ Wb, float* __restrict__ scale, float* __restrict__ bias,
    float4* __restrict__ pts)
{
    const int t = blockIdx.x * 256 + threadIdx.x;   // grid covers B*N = 32768
    if (t < CCH * CCH) Wb[t] = f2bf(W[t]);
    if (t < CCH) {
        const float s = gamma[t] / sqrtf(rvar[t] + 1e-5f);
        scale[t] = s;
        bias[t]  = beta[t] - rmean[t] * s;
    }
    {
        #pragma clang fp contract(off)
        const float px = xyz[3 * t + 0];
        const float py = xyz[3 * t + 1];
        const float pz = xyz[3 * t + 2];
        const float s  = px * px + py * py + pz * pz;   // matches ref s = sum(xyz*xyz)
        pts[t] = make_float4(px, py, pz, s);
    }
}

// KNN v3: buffered top-k with bitonic flush. 4 queries per wave; lane = g*16+s.
//
// Selection semantics (== reference top_k): final result is the 16 smallest
// candidates by (d2, j) lexicographic, emitted in lex order. We maintain:
//  - list (lhi,llo): sorted 16 keys (mono(d2)<<32 | j) across the group's 16
//    lanes, exact running top-16 of all APPENDED candidates.
//  - buffer (bufD,bufJ): up to 16 unsorted survivors, appended in parallel
//    (one ds_permute push per triggered sub-chunk; rank via popcount).
//  - tau: d2 of list[15] as of last flush. Strict < filter is correct: a
//    later candidate with d2 == tau has larger j than every listed entry,
//    so it can never enter the top-16.
// Flush (when any group's buffer would overflow): bitonic-sort the 16
// buffered keys (10 ds_swizzle XOR stages, compile-time patterns), bitonic-
// merge with the sorted list (reverse + elementwise min + 4 clean stages),
// refresh tau. mono() maps float bits to order-preserving uint; sentinel
// 0xFF7FFFFF == mono(3.4e38) so empty slots sort last and tau inverts to
// +big on early flushes. d2 expression is bit-identical to the reference.
#define PK_(h, l) ((((unsigned long long)(h)) << 32) | (unsigned long long)(l))

__global__ __launch_bounds__(256) void knn_kernel(
    const float4* __restrict__ pts, unsigned short* __restrict__ knn)
{
    const int lane = threadIdx.x & 63;
    const int wid  = threadIdx.x >> 6;
    const int g    = lane >> 4;                 // group (query) 0..3
    const int s    = lane & 15;                 // slot within group
    const int wq   = blockIdx.x * 16 + wid * 4; // first query of this wave
    const int b    = wq >> 12;                  // 4 queries never cross a batch
    const int i    = (wq & 4095) + g;           // this lane's query
    const float4* pb = pts + (b << 12);

    const float4 q = pb[i];                     // group-uniform

    const unsigned SENT_HI = 0xFF7FFFFFu;       // mono(+3.4e38)
    const unsigned SENT_LO = 0xFFFFFFFFu;

    unsigned lhi = SENT_HI, llo = SENT_LO;      // sorted top-16 list (asc)
    float bufD = 0.f;                           // survivor buffer (slot s)
    int   bufJ = 0;
    int   cnt  = 0;                             // valid buffer entries (group-uniform)
    float tau  = 3.4e38f;
    const int gsh = g << 4;

    auto flush = [&]() {
        // build keys from buffer; invalid slots -> sentinel
        const unsigned u = __float_as_uint(bufD);
        unsigned khi = (u & 0x80000000u) ? ~u : (u | 0x80000000u);
        unsigned klo = (unsigned)bufJ;
        const bool inval = (s >= cnt);
        khi = inval ? SENT_HI : khi;
        klo = inval ? SENT_LO : klo;
        // bitonic sort, ascending across the 16 group lanes
        #define CE_(K, J, OFF) { \
            const unsigned ohi = (unsigned)__builtin_amdgcn_ds_swizzle((int)khi, OFF); \
            const unsigned olo = (unsigned)__builtin_amdgcn_ds_swizzle((int)klo, OFF); \
            const bool olt = PK_(ohi, olo) < PK_(khi, klo); \
            const bool sel = (((s & (J)) == 0) == ((s & (K)) == 0)); \
            const bool tk  = sel ? olt : !olt; \
            khi = tk ? ohi : khi; klo = tk ? olo : klo; }
        CE_(2, 1, 0x041F)
        CE_(4, 2, 0x081F)  CE_(4, 1, 0x041F)
        CE_(8, 4, 0x101F)  CE_(8, 2, 0x081F)  CE_(8, 1, 0x041F)
        CE_(16, 8, 0x201F) CE_(16, 4, 0x101F) CE_(16, 2, 0x081F) CE_(16, 1, 0x041F)
        #undef CE_
        // merge with list: reverse buffer, elementwise min, 4 clean stages
        {
            const unsigned rhi = (unsigned)__builtin_amdgcn_ds_swizzle((int)khi, 0x3C1F);
            const unsigned rlo = (unsigned)__builtin_amdgcn_ds_swizzle((int)klo, 0x3C1F);
            const bool rlt = PK_(rhi, rlo) < PK_(lhi, llo);
            lhi = rlt ? rhi : lhi; llo = rlt ? rlo : llo;
        }
        #define MC_(J, OFF) { \
            const unsigned ohi = (unsigned)__builtin_amdgcn_ds_swizzle((int)lhi, OFF); \
            const unsigned olo = (unsigned)__builtin_amdgcn_ds_swizzle((int)llo, OFF); \
            const bool olt = PK_(ohi, olo) < PK_(lhi, llo); \
            const bool tk  = ((s & (J)) == 0) ? olt : !olt; \
            lhi = tk ? ohi : lhi; llo = tk ? olo : llo; }
        MC_(8, 0x201F) MC_(4, 0x101F) MC_(2, 0x081F) MC_(1, 0x041F)
        #undef MC_
        // tau = inv-mono(list[15].hi)  (broadcast slot 15 within each 16-group)
        const unsigned thi = (unsigned)__builtin_amdgcn_ds_swizzle((int)lhi, 0x01F0);
        tau = __uint_as_float((thi & 0x80000000u) ? (thi & 0x7FFFFFFFu) : ~thi);
        cnt = 0;
    };

    // filter + parallel append for one 16-candidate sub-chunk
    #define SUB_(DD, C, JB) { \
        const unsigned long long mask = __ballot((DD) < tau); \
        if (mask) { \
            const unsigned sub = (unsigned)((mask >> gsh) & 0xFFFFull); \
            const int m = __popc(sub); \
            if (__any(cnt + m > 15)) flush(); \
            const bool surv = (sub >> s) & 1u; \
            const int rank  = __popc(sub & ((1u << s) - 1u)); \
            const int dest  = surv ? (cnt + rank) : 15;   /* slot 15 always free */ \
            const int addr  = (gsh | dest) << 2; \
            const int nd = __builtin_amdgcn_ds_permute(addr, __float_as_int(DD)); \
            const int nj = __builtin_amdgcn_ds_permute(addr, (JB) + ((C) << 4) + s); \
            const bool got = (s >= cnt) & (s < cnt + m); \
            bufD = got ? __int_as_float(nd) : bufD; \
            bufJ = got ? nj : bufJ; \
            cnt += m; \
        } }

    const float4* lp = pb + s;                  // block 0 base for this lane
    float4 a0 = lp[0], a1 = lp[16], a2 = lp[32], a3 = lp[48];
    lp += 64;

    #pragma unroll 1
    for (int it = 0; it < 64; ++it) {
        // prefetch next block (clamped on last iter; values unused)
        const float4* np = (it < 63) ? lp : pb;
        const float4 n0 = np[0], n1 = np[16], n2 = np[32], n3 = np[48];
        float dd0, dd1, dd2, dd3;
        {
            #pragma clang fp contract(off)
            dd0 = (q.w + a0.w) - 2.0f * (q.x * a0.x + q.y * a0.y + q.z * a0.z);
            dd1 = (q.w + a1.w) - 2.0f * (q.x * a1.x + q.y * a1.y + q.z * a1.z);
            dd2 = (q.w + a2.w) - 2.0f * (q.x * a2.x + q.y * a2.y + q.z * a2.z);
            dd3 = (q.w + a3.w) - 2.0f * (q.x * a3.x + q.y * a3.y + q.z * a3.z);
        }
        const int jbase = it * 64;
        SUB_(dd0, 0, jbase)
        SUB_(dd1, 1, jbase)
        SUB_(dd2, 2, jbase)
        SUB_(dd3, 3, jbase)
        a0 = n0; a1 = n1; a2 = n2; a3 = n3;
        lp += 64;
    }
    #undef SUB_
    flush();                                    // drain remaining buffer

    unsigned short* o = knn + ((((size_t)b << 12) + i) << 4);
    o[s] = (unsigned short)llo;                 // j of s-th smallest (d2, j)
}

// Dense GEMM: Z[g, c] = sum_k xTb[g, k] * W[c, k], Z bf16 [B*N, C].
// Wave = 16 rows x 128 cols; verified fragment mappings (A: m=lane&15,
// k=(lane>>4)*8+j; B: n=lane&15, same k-slice; C/D: col=lane&15,
// row=(lane>>4)*4+reg). W staged in LDS, pitch 136.
__global__ __launch_bounds__(256) void zgemm_kernel(
    const short* __restrict__ xTb, const short* __restrict__ Wb,
    short* __restrict__ Zb)
{
    __shared__ short sW[CCH * 136];
    const int lane = threadIdx.x & 63;
    const int wid  = threadIdx.x >> 6;
    const int kl   = lane & 15;
    const int q8   = (lane >> 4) * 8;

    #pragma unroll
    for (int it = 0; it < 8; ++it) {             // stage W: 16384 elems
        const int e = (it * 256 + threadIdx.x) * 8;
        const int r = e >> 7, c = e & 127;
        *(bf16x8*)(sW + r * 136 + c) = *(const bf16x8*)(Wb + e);
    }

    const int    G    = blockIdx.x * 64 + wid * 16 + kl;   // A-row (flat B*N)
    const size_t arow = (size_t)G * CCH;
    __syncthreads();

    const f32x4 zero = {0.f, 0.f, 0.f, 0.f};
    f32x4 acc[8];
    #pragma unroll
    for (int t = 0; t < 8; ++t) acc[t] = zero;

    #pragma unroll
    for (int kk = 0; kk < 4; ++kk) {
        const bf16x8 a = *(const bf16x8*)(xTb + arow + kk * 32 + q8);
        #pragma unroll
        for (int t = 0; t < 8; ++t) {
            const bf16x8 bf = *(const bf16x8*)(sW + (t * 16 + kl) * 136 + kk * 32 + q8);
            acc[t] = __builtin_amdgcn_mfma_f32_16x16x32_bf16(a, bf, acc[t], 0, 0, 0);
        }
    }

    const int rbase = blockIdx.x * 64 + wid * 16 + (lane >> 4) * 4;
    #pragma unroll
    for (int t = 0; t < 8; ++t)
        #pragma unroll
        for (int r = 0; r < 4; ++r)
            Zb[(size_t)(rbase + r) * CCH + t * 16 + kl] = f2bf(acc[t][r]);
}

// Gather + BN + ReLU + max-over-16, then coalesced store via LDS transpose.
// Block = 16 points; wave w handles 4 points serially; lane l covers channels
// 2l, 2l+1 (one dword per Z-row read; full 256B row per wave, coalesced).
__global__ __launch_bounds__(256) void gmax_kernel(
    const short* __restrict__ Zb, const unsigned short* __restrict__ knn,
    const float* __restrict__ scale, const float* __restrict__ bias,
    float* __restrict__ out)
{
    __shared__ float sm[16][132];
    const int lane = threadIdx.x & 63;
    const int wid  = threadIdx.x >> 6;
    const int n0   = blockIdx.x * 16;           // flat point base (B*N)
    const int b    = blockIdx.x >> 8;           // 256 blocks per batch
    const float s0 = scale[2 * lane],   s1 = scale[2 * lane + 1];
    const float t0 = bias[2 * lane],    t1 = bias[2 * lane + 1];

    for (int p = 0; p < 4; ++p) {
        const int n = n0 + wid * 4 + p;         // flat
        const unsigned short* kr = knn + (size_t)n * 16;
        float m0 = 0.f, m1 = 0.f;               // relu floor
        #pragma unroll
        for (int k = 0; k < 16; ++k) {
            const int r = (int)kr[k];           // within-batch row
            const unsigned v = *(const unsigned*)(Zb + ((size_t)(b * NPTS + r)) * CCH + 2 * lane);
            const float z0 = __uint_as_float(v << 16);
            const float z1 = __uint_as_float(v & 0xFFFF0000u);
            m0 = fmaxf(m0, s0 * z0 + t0);
            m1 = fmaxf(m1, s1 * z1 + t1);
        }
        sm[wid * 4 + p][2 * lane]     = m0;
        sm[wid * 4 + p][2 * lane + 1] = m1;
    }
    __syncthreads();

    const int c    = threadIdx.x & 127;
    const int half = threadIdx.x >> 7;
    float v[8];
    #pragma unroll
    for (int i = 0; i < 8; ++i) v[i] = sm[half * 8 + i][c];
    float4 f0 = {v[0], v[1], v[2], v[3]};
    float4 f1 = {v[4], v[5], v[6], v[7]};
    float* op = out + ((size_t)(b * CCH + c)) * NPTS + (n0 & 4095) + half * 8;
    *(float4*)op       = f0;
    *(float4*)(op + 4) = f1;
}

extern "C" void kernel_launch(void* const* d_in, const int* in_sizes, int n_in,
                              void* d_out, int out_size, void* d_ws, size_t ws_size,
                              hipStream_t stream)
{
    const float* xyz   = (const float*)d_in[0];
    const float* x     = (const float*)d_in[1];
    const float* W     = (const float*)d_in[2];
    const float* gamma = (const float*)d_in[3];
    const float* beta  = (const float*)d_in[4];
    const float* rmean = (const float*)d_in[5];
    const float* rvar  = (const float*)d_in[6];
    float* out = (float*)d_out;

    char* ws = (char*)d_ws;
    short*          xTb   = (short*)(ws);
    short*          Wb    = (short*)(ws + 8388608);
    float*          scale = (float*)(ws + 8421376);
    float*          bias  = (float*)(ws + 8421888);
    float4*         pts   = (float4*)(ws + 8422400);
    unsigned short* knn   = (unsigned short*)(ws + 8946688);
    short*          Zb    = (short*)(ws + 9995264);

    transpose_kernel<<<BATCH * 64 * 2, 256, 0, stream>>>(x, xTb);
    small_prep_kernel<<<BATCH * NPTS / 256, 256, 0, stream>>>(
        xyz, W, gamma, beta, rmean, rvar, Wb, scale, bias, pts);
    knn_kernel<<<BATCH * NPTS / 16, 256, 0, stream>>>(pts, knn);
    zgemm_kernel<<<BATCH * NPTS / 64, 256, 0, stream>>>(xTb, Wb, Zb);
    gmax_kernel<<<BATCH * NPTS / 16, 256, 0, stream>>>(Zb, knn, scale, bias, out);
}